// Round 1
// 92.848 us; speedup vs baseline: 1.0519x; 1.0519x over previous
//
#include <hip/hip_runtime.h>
#include <hip/hip_fp16.h>

#define BN 4096
#define DIM 256
#define NBLK 32              // 4096/128 row-blocks
#define NPAIR 528            // NBLK*(NBLK+1)/2 upper-tri block pairs
#define MARGIN_F 0.3f
#define NEG_FILL_F 1e9f
#define HP_SENT_BITS 0xBF800000  // bits of -1.0f: "no positive seen"

typedef __attribute__((ext_vector_type(8))) _Float16 f16x8;
typedef __attribute__((ext_vector_type(4))) float f32x4;

// ---------------- prep: norms (exact fp32) + red zero + fp16 panel ---------------
// Eh global layout is chunk-major: [kc = k/8][row][8 f16], 16B per (kc,row) chunk.
__global__ __launch_bounds__(256) void tl_prep(const float* __restrict__ E,
                                               float* __restrict__ norms,
                                               float* __restrict__ red,
                                               ushort* __restrict__ Eh) {
    const int tid  = threadIdx.x;
    const int lane = tid & 63;
    const int row  = blockIdx.x * 4 + (tid >> 6);

    float4 v = reinterpret_cast<const float4*>(E + (size_t)row * DIM)[lane];
    float f[4] = {v.x, v.y, v.z, v.w};
    ushort hb[4];
    float s = 0.0f;
    #pragma unroll
    for (int q = 0; q < 4; ++q) {
        s += f[q] * f[q];                       // norm from ORIGINAL fp32 (exact)
        hb[q] = __half_as_ushort(__float2half(f[q]));   // RN convert
    }
    // lane holds k = lane*4..lane*4+3 -> chunk kc = lane/2, half = lane&1
    const int kc = lane >> 1, half = lane & 1;
    const size_t co = (((size_t)(kc * BN + row)) << 3) + (size_t)(half * 4);
    *reinterpret_cast<ushort4*>(Eh + co) = make_ushort4(hb[0], hb[1], hb[2], hb[3]);

    #pragma unroll
    for (int m = 32; m; m >>= 1) s += __shfl_xor(s, m, 64);
    if (lane == 0) norms[row] = s;
    if (blockIdx.x == 0 && tid < 3) red[tid] = 0.0f;  // [0]=sum [1]=cnt [2]=ticket
}

// ---------------- main: barrier-free fp16 MFMA Gram, operands direct from L2 -----
// One block per upper-tri 128x128 pair, 4 waves each owning a 64x64 sub-tile.
// Eh (2 MB) is L2-resident: fragments are loaded straight from global, register
// double-buffered over 8 K=32 steps. NO operand LDS, NO main-loop barriers ->
// 2 KB LDS, all 528 blocks resident in ONE round (was 2 rounds @ 64 KB LDS).
// Epilogue reduces in d^2 space (sqrt is monotone; deferred to tl_reduce).
__global__ __launch_bounds__(256) void tl_main(const ushort* __restrict__ Eh,
                                               const int* __restrict__ labels,
                                               const float* __restrict__ norms,
                                               float* __restrict__ pHP,
                                               float* __restrict__ pHN) {
    __shared__ int comb[512];            // [0:128) rHP [128) rHN [256) cHP [384) cHN

    const int tid  = threadIdx.x;
    const int lane = tid & 63;
    const int wave = tid >> 6;
    const int wy = wave >> 1, wx = wave & 1;
    const int quad = lane >> 4, l15 = lane & 15;

    // decode blockIdx -> (ib <= jb) upper-tri pair
    int t = blockIdx.x, ib = 0, off = 0;
    while (off + (NBLK - ib) <= t) { off += NBLK - ib; ++ib; }
    const int jb = ib + (t - off);
    const int i0 = ib * 128, j0 = jb * 128;

    f32x4 acc[4][4];
    #pragma unroll
    for (int r = 0; r < 4; ++r)
        #pragma unroll
        for (int c = 0; c < 4; ++c)
            acc[r][c] = (f32x4){0.f, 0.f, 0.f, 0.f};

    // per-lane fragment addresses: chunk (s*4 + quad), rows below (ushort units)
    const ushort* baseQ = Eh + (size_t)quad * (BN * 8);
    int rA[4], rB[4];
    #pragma unroll
    for (int r = 0; r < 4; ++r) rA[r] = (i0 + wy * 64 + r * 16 + l15) * 8;
    #pragma unroll
    for (int c = 0; c < 4; ++c) rB[c] = (j0 + wx * 64 + c * 16 + l15) * 8;

    f16x8 a0[4], b0[4], a1[4], b1[4];
    auto LD = [&](f16x8 (&A)[4], f16x8 (&B)[4], int s) {
        const size_t so = (size_t)s * (4u * BN * 8u);
        #pragma unroll
        for (int r = 0; r < 4; ++r)
            A[r] = *reinterpret_cast<const f16x8*>(baseQ + so + (size_t)rA[r]);
        #pragma unroll
        for (int c = 0; c < 4; ++c)
            B[c] = *reinterpret_cast<const f16x8*>(baseQ + so + (size_t)rB[c]);
    };
    auto MM = [&](f16x8 (&A)[4], f16x8 (&B)[4]) {
        #pragma unroll
        for (int c = 0; c < 4; ++c)
            #pragma unroll
            for (int r = 0; r < 4; ++r)
                acc[r][c] = __builtin_amdgcn_mfma_f32_16x16x32_f16(A[r], B[c], acc[r][c], 0, 0, 0);
    };

    // software pipeline: loads of step s+1 in flight under MFMAs of step s
    LD(a0, b0, 0);
    LD(a1, b1, 1); MM(a0, b0);
    LD(a0, b0, 2); MM(a1, b1);
    LD(a1, b1, 3); MM(a0, b0);
    LD(a0, b0, 4); MM(a1, b1);
    LD(a1, b1, 5); MM(a0, b0);
    LD(a0, b0, 6); MM(a1, b1);
    LD(a1, b1, 7); MM(a0, b0);
    MM(a1, b1);

    // ---- epilogue: dots -> d^2 -> masked row & col stats (d^2 space; sqrt later)
    // C layout (16x16x32): col = lane&15, row = quad*4 + reg  [m89/m91, dtype-indep]
    const int rowBase = i0 + wy * 64;
    const int colBase = j0 + wx * 64;

    float nrow[4][4]; int lrow[4][4];
    #pragma unroll
    for (int r = 0; r < 4; ++r)
        #pragma unroll
        for (int e = 0; e < 4; ++e) {
            const int g = rowBase + r * 16 + quad * 4 + e;
            nrow[r][e] = norms[g];
            lrow[r][e] = labels[g];
        }
    float ncol[4]; int lcol[4];
    #pragma unroll
    for (int c = 0; c < 4; ++c) {
        const int g = colBase + c * 16 + l15;
        ncol[c] = norms[g];
        lcol[c] = labels[g];
    }

    float rmax[4][4], rmin[4][4], cmax[4], cmin[4];
    #pragma unroll
    for (int r = 0; r < 4; ++r)
        #pragma unroll
        for (int e = 0; e < 4; ++e) { rmax[r][e] = -1.0f; rmin[r][e] = NEG_FILL_F; }
    #pragma unroll
    for (int c = 0; c < 4; ++c) { cmax[c] = -1.0f; cmin[c] = NEG_FILL_F; }

    #pragma unroll
    for (int c = 0; c < 4; ++c) {
        const int gcol = colBase + c * 16 + l15;
        #pragma unroll
        for (int r = 0; r < 4; ++r) {
            #pragma unroll
            for (int e = 0; e < 4; ++e) {
                const int grow = rowBase + r * 16 + quad * 4 + e;
                float d2 = nrow[r][e] + ncol[c] - 2.0f * acc[r][c][e];
                d2 = fmaxf(d2, 0.0f);            // d==0 <=> d2==0: guard-free
                if (lrow[r][e] == lcol[c]) {
                    if (grow != gcol) {
                        rmax[r][e] = fmaxf(rmax[r][e], d2);
                        cmax[c]    = fmaxf(cmax[c], d2);
                    }
                } else {
                    rmin[r][e] = fminf(rmin[r][e], d2);
                    cmin[c]    = fminf(cmin[c], d2);
                }
            }
        }
    }

    #pragma unroll
    for (int m = 1; m <= 8; m <<= 1) {          // row stats across lane bits 0..3
        #pragma unroll
        for (int r = 0; r < 4; ++r)
            #pragma unroll
            for (int e = 0; e < 4; ++e) {
                rmax[r][e] = fmaxf(rmax[r][e], __shfl_xor(rmax[r][e], m, 64));
                rmin[r][e] = fminf(rmin[r][e], __shfl_xor(rmin[r][e], m, 64));
            }
    }
    #pragma unroll
    for (int m = 16; m <= 32; m <<= 1) {        // col stats across quads
        #pragma unroll
        for (int c = 0; c < 4; ++c) {
            cmax[c] = fmaxf(cmax[c], __shfl_xor(cmax[c], m, 64));
            cmin[c] = fminf(cmin[c], __shfl_xor(cmin[c], m, 64));
        }
    }

    // block-level combine in LDS (CU-local atomics; signed-int encoding so the
    // -1.0f sentinel orders correctly), then PLAIN global stores to partial slots.
    int*      srhp = comb;                                   // [128]
    unsigned* srhn = reinterpret_cast<unsigned*>(comb + 128);
    int*      schp = comb + 256;
    unsigned* schn = reinterpret_cast<unsigned*>(comb + 384);
    if (tid < 128) {
        srhp[tid] = (int)HP_SENT_BITS;
        srhn[tid] = __float_as_uint(NEG_FILL_F);
        schp[tid] = (int)HP_SENT_BITS;
        schn[tid] = __float_as_uint(NEG_FILL_F);
    }
    __syncthreads();
    if (l15 == 0) {   // lanes 0,16,32,48 hold row results for their quad
        #pragma unroll
        for (int r = 0; r < 4; ++r)
            #pragma unroll
            for (int e = 0; e < 4; ++e) {
                const int lr = wy * 64 + r * 16 + quad * 4 + e;
                atomicMax(&srhp[lr], __float_as_int(rmax[r][e]));
                atomicMin(&srhn[lr], __float_as_uint(rmin[r][e]));
            }
    }
    if (quad == 0) {  // lanes 0..15 hold col results
        #pragma unroll
        for (int c = 0; c < 4; ++c) {
            const int lc = wx * 64 + c * 16 + l15;
            atomicMax(&schp[lc], __float_as_int(cmax[c]));
            atomicMin(&schn[lc], __float_as_uint(cmin[c]));
        }
    }
    __syncthreads();
    if (tid < 128) {
        float rp = __int_as_float(srhp[tid]);
        float rn = __uint_as_float(srhn[tid]);
        const float cp = __int_as_float(schp[tid]);
        const float cn = __uint_as_float(schn[tid]);
        if (ib == jb) {
            pHP[(size_t)jb * BN + i0 + tid] = fmaxf(rp, cp);   // diagonal: combine
            pHN[(size_t)jb * BN + i0 + tid] = fminf(rn, cn);
        } else {
            pHP[(size_t)jb * BN + i0 + tid] = rp;   // row-part -> slot jb
            pHN[(size_t)jb * BN + i0 + tid] = rn;
            pHP[(size_t)ib * BN + j0 + tid] = cp;   // col-part -> slot ib
            pHN[(size_t)ib * BN + j0 + tid] = cn;
        }
    }
}

// ------- reduce: fold 32 d^2 partial slots per row, sqrt once, accumulate loss ---
__global__ __launch_bounds__(64) void tl_reduce(const float* __restrict__ pHP,
                                                const float* __restrict__ pHN,
                                                float* __restrict__ red,
                                                float* __restrict__ out) {
    const int i = blockIdx.x * 64 + threadIdx.x;     // one row per thread
    float hp2 = -1.0f, hn2 = NEG_FILL_F;
    #pragma unroll
    for (int s = 0; s < NBLK; ++s) {
        hp2 = fmaxf(hp2, pHP[(size_t)s * BN + i]);   // coalesced per wave
        hn2 = fminf(hn2, pHN[(size_t)s * BN + i]);
    }
    const bool valid = (hp2 >= 0.0f) && (hn2 < NEG_FILL_F);  // has_pos && has_neg
    const float hp = sqrtf(fmaxf(hp2, 0.0f));        // sqrt(max d^2) == max d
    const float hn = sqrtf(hn2);
    const float per = fmaxf(hp - hn + MARGIN_F, 0.0f);
    float s_ = valid ? per : 0.0f;
    float c_ = valid ? 1.0f : 0.0f;
    #pragma unroll
    for (int m = 32; m; m >>= 1) {
        s_ += __shfl_xor(s_, m, 64);
        c_ += __shfl_xor(c_, m, 64);
    }
    if (threadIdx.x == 0) {
        atomicAdd(&red[0], s_);
        atomicAdd(&red[1], c_);
        __threadfence();
        const unsigned ticket = atomicAdd(reinterpret_cast<unsigned*>(&red[2]), 1u);
        if (ticket == gridDim.x - 1) {               // last block finalizes
            const float S2 = atomicAdd(&red[0], 0.0f);   // atomic read (RMW-ordered)
            const float C2 = atomicAdd(&red[1], 0.0f);
            out[0] = (C2 > 0.0f) ? (S2 / fmaxf(C2, 1.0f)) : 0.0f;
        }
    }
}

extern "C" void kernel_launch(void* const* d_in, const int* in_sizes, int n_in,
                              void* d_out, int out_size, void* d_ws, size_t ws_size,
                              hipStream_t stream) {
    const float* E      = (const float*)d_in[0];
    const int*   labels = (const int*)d_in[1];

    float*  ws    = (float*)d_ws;
    float*  norms = ws;                            // [4096] f32
    float*  red   = ws + 4096;                     // [3] f32 (sum, cnt, ticket)
    float*  pHP   = ws + 8192;                     // [32][4096] f32 = 512 KB (d^2)
    float*  pHN   = ws + 8192 + NBLK * BN;         // [32][4096] f32 = 512 KB (d^2)
    ushort* Eh    = (ushort*)(ws + 8192 + 2 * NBLK * BN);  // [32][4096][8] f16 = 2 MB

    tl_prep<<<BN / 4, 256, 0, stream>>>(E, norms, red, Eh);
    tl_main<<<NPAIR, 256, 0, stream>>>(Eh, labels, norms, pHP, pHN);
    tl_reduce<<<BN / 64, 64, 0, stream>>>(pHP, pHN, red, (float*)d_out);
}

// Round 2
// 80.420 us; speedup vs baseline: 1.2144x; 1.1545x over previous
//
#include <hip/hip_runtime.h>
#include <hip/hip_fp16.h>

#define BN 4096
#define DIM 256
#define NBLK 32              // 4096/128 row-blocks
#define NPAIR 528            // NBLK*(NBLK+1)/2 upper-tri block pairs
#define MARGIN_F 0.3f
#define NEG_FILL_F 1e9f
#define HP_SENT_BITS 0xBF800000  // bits of -1.0f: "no positive seen"

typedef __attribute__((ext_vector_type(8))) _Float16 f16x8;
typedef __attribute__((ext_vector_type(4))) float f32x4;

// ---------------- prep: norms (exact fp32) + red zero + fp16 panel ---------------
// Eh global layout is chunk-major: [kc = k/8][row][8 f16], 16B per (kc,row) chunk.
// Stores now staged through LDS: 16B/lane, 4-row (64B) contiguity per kc
// (was: raw 8B scatter at 32KB stride -> worst-case write coalescing).
__global__ __launch_bounds__(256) void tl_prep(const float* __restrict__ E,
                                               float* __restrict__ norms,
                                               float* __restrict__ red,
                                               ushort* __restrict__ Eh) {
    __shared__ ushort sh[4][272];            // 272-pad: 544B row stride, 16B-aligned
    const int tid  = threadIdx.x;
    const int lane = tid & 63;
    const int wrow = tid >> 6;               // 0..3: row within block
    const int row0 = blockIdx.x * 4;
    const int row  = row0 + wrow;

    float4 v = reinterpret_cast<const float4*>(E + (size_t)row * DIM)[lane];
    float f[4] = {v.x, v.y, v.z, v.w};
    ushort hb[4];
    float s = 0.0f;
    #pragma unroll
    for (int q = 0; q < 4; ++q) {
        s += f[q] * f[q];                       // norm from ORIGINAL fp32 (exact)
        hb[q] = __half_as_ushort(__float2half(f[q]));   // RN convert
    }
    // lane holds cols lane*4..lane*4+3 -> LDS row-major (2-way bank alias: free)
    *reinterpret_cast<ushort4*>(&sh[wrow][lane * 4]) = make_ushort4(hb[0], hb[1], hb[2], hb[3]);

    #pragma unroll
    for (int m = 32; m; m >>= 1) s += __shfl_xor(s, m, 64);
    if (lane == 0) norms[row] = s;
    if (blockIdx.x == 0 && tid < 3) red[tid] = 0.0f;  // [0]=sum [1]=cnt [2]=ticket

    __syncthreads();
    // 4 rows x 32 kc = 128 chunks of 16B; threads 0..127, rows fastest -> 64B runs
    if (tid < 128) {
        const int kc = tid >> 2, r = tid & 3;
        const f16x8 frag = *reinterpret_cast<const f16x8*>(&sh[r][kc * 8]);
        *reinterpret_cast<f16x8*>(Eh + (((size_t)(kc * BN + row0 + r)) << 3)) = frag;
    }
}

// ---------------- main: barrier-free fp16 MFMA Gram, operands direct from L2 -----
// One block per upper-tri 128x128 pair, 4 waves each owning a 64x64 sub-tile.
// Eh (2 MB) is L2-resident: fragments loaded straight from global, register
// double-buffered over 8 K=32 steps. NO operand LDS, NO main-loop barriers.
// __launch_bounds__(256,3): cap VGPR<=~170 -> 3 blocks/CU -> all 528 blocks
// resident in ONE round (2 blocks/CU = 512 slots forces a serial 16-block tail).
__global__ __launch_bounds__(256, 3) void tl_main(const ushort* __restrict__ Eh,
                                                  const int* __restrict__ labels,
                                                  const float* __restrict__ norms,
                                                  float* __restrict__ pHP,
                                                  float* __restrict__ pHN) {
    __shared__ int comb[512];            // [0:128) rHP [128) rHN [256) cHP [384) cHN

    const int tid  = threadIdx.x;
    const int lane = tid & 63;
    const int wave = tid >> 6;
    const int wy = wave >> 1, wx = wave & 1;
    const int quad = lane >> 4, l15 = lane & 15;

    // decode blockIdx -> (ib <= jb) upper-tri pair
    int t = blockIdx.x, ib = 0, off = 0;
    while (off + (NBLK - ib) <= t) { off += NBLK - ib; ++ib; }
    const int jb = ib + (t - off);
    const int i0 = ib * 128, j0 = jb * 128;

    f32x4 acc[4][4];
    #pragma unroll
    for (int r = 0; r < 4; ++r)
        #pragma unroll
        for (int c = 0; c < 4; ++c)
            acc[r][c] = (f32x4){0.f, 0.f, 0.f, 0.f};

    // per-lane fragment addresses: chunk (s*4 + quad), rows below (ushort units)
    const ushort* baseQ = Eh + (size_t)quad * (BN * 8);
    int rA[4], rB[4];
    #pragma unroll
    for (int r = 0; r < 4; ++r) rA[r] = (i0 + wy * 64 + r * 16 + l15) * 8;
    #pragma unroll
    for (int c = 0; c < 4; ++c) rB[c] = (j0 + wx * 64 + c * 16 + l15) * 8;

    f16x8 a0[4], b0[4], a1[4], b1[4];
    auto LD = [&](f16x8 (&A)[4], f16x8 (&B)[4], int s) {
        const size_t so = (size_t)s * (4u * BN * 8u);
        #pragma unroll
        for (int r = 0; r < 4; ++r)
            A[r] = *reinterpret_cast<const f16x8*>(baseQ + so + (size_t)rA[r]);
        #pragma unroll
        for (int c = 0; c < 4; ++c)
            B[c] = *reinterpret_cast<const f16x8*>(baseQ + so + (size_t)rB[c]);
    };
    auto MM = [&](f16x8 (&A)[4], f16x8 (&B)[4]) {
        #pragma unroll
        for (int c = 0; c < 4; ++c)
            #pragma unroll
            for (int r = 0; r < 4; ++r)
                acc[r][c] = __builtin_amdgcn_mfma_f32_16x16x32_f16(A[r], B[c], acc[r][c], 0, 0, 0);
    };

    // software pipeline: loads of step s+1 in flight under MFMAs of step s
    LD(a0, b0, 0);
    LD(a1, b1, 1); MM(a0, b0);
    LD(a0, b0, 2); MM(a1, b1);
    LD(a1, b1, 3); MM(a0, b0);
    LD(a0, b0, 4); MM(a1, b1);
    LD(a1, b1, 5); MM(a0, b0);
    LD(a0, b0, 6); MM(a1, b1);
    LD(a1, b1, 7); MM(a0, b0);
    MM(a1, b1);

    // ---- epilogue: dots -> d^2 -> masked row & col stats (d^2 space; sqrt later)
    // C layout (16x16x32): col = lane&15, row = quad*4 + reg  [m89/m91, dtype-indep]
    const int rowBase = i0 + wy * 64;
    const int colBase = j0 + wx * 64;

    float nrow[4][4]; int lrow[4][4];
    #pragma unroll
    for (int r = 0; r < 4; ++r)
        #pragma unroll
        for (int e = 0; e < 4; ++e) {
            const int g = rowBase + r * 16 + quad * 4 + e;
            nrow[r][e] = norms[g];
            lrow[r][e] = labels[g];
        }
    float ncol[4]; int lcol[4];
    #pragma unroll
    for (int c = 0; c < 4; ++c) {
        const int g = colBase + c * 16 + l15;
        ncol[c] = norms[g];
        lcol[c] = labels[g];
    }

    float rmax[4][4], rmin[4][4], cmax[4], cmin[4];
    #pragma unroll
    for (int r = 0; r < 4; ++r)
        #pragma unroll
        for (int e = 0; e < 4; ++e) { rmax[r][e] = -1.0f; rmin[r][e] = NEG_FILL_F; }
    #pragma unroll
    for (int c = 0; c < 4; ++c) { cmax[c] = -1.0f; cmin[c] = NEG_FILL_F; }

    #pragma unroll
    for (int c = 0; c < 4; ++c) {
        const int gcol = colBase + c * 16 + l15;
        #pragma unroll
        for (int r = 0; r < 4; ++r) {
            #pragma unroll
            for (int e = 0; e < 4; ++e) {
                const int grow = rowBase + r * 16 + quad * 4 + e;
                float d2 = nrow[r][e] + ncol[c] - 2.0f * acc[r][c][e];
                d2 = fmaxf(d2, 0.0f);            // d==0 <=> d2==0: guard-free
                if (lrow[r][e] == lcol[c]) {
                    if (grow != gcol) {
                        rmax[r][e] = fmaxf(rmax[r][e], d2);
                        cmax[c]    = fmaxf(cmax[c], d2);
                    }
                } else {
                    rmin[r][e] = fminf(rmin[r][e], d2);
                    cmin[c]    = fminf(cmin[c], d2);
                }
            }
        }
    }

    #pragma unroll
    for (int m = 1; m <= 8; m <<= 1) {          // row stats across lane bits 0..3
        #pragma unroll
        for (int r = 0; r < 4; ++r)
            #pragma unroll
            for (int e = 0; e < 4; ++e) {
                rmax[r][e] = fmaxf(rmax[r][e], __shfl_xor(rmax[r][e], m, 64));
                rmin[r][e] = fminf(rmin[r][e], __shfl_xor(rmin[r][e], m, 64));
            }
    }
    #pragma unroll
    for (int m = 16; m <= 32; m <<= 1) {        // col stats across quads
        #pragma unroll
        for (int c = 0; c < 4; ++c) {
            cmax[c] = fmaxf(cmax[c], __shfl_xor(cmax[c], m, 64));
            cmin[c] = fminf(cmin[c], __shfl_xor(cmin[c], m, 64));
        }
    }

    // block-level combine in LDS (CU-local atomics; signed-int encoding so the
    // -1.0f sentinel orders correctly), then PLAIN global stores to partial slots.
    int*      srhp = comb;                                   // [128]
    unsigned* srhn = reinterpret_cast<unsigned*>(comb + 128);
    int*      schp = comb + 256;
    unsigned* schn = reinterpret_cast<unsigned*>(comb + 384);
    if (tid < 128) {
        srhp[tid] = (int)HP_SENT_BITS;
        srhn[tid] = __float_as_uint(NEG_FILL_F);
        schp[tid] = (int)HP_SENT_BITS;
        schn[tid] = __float_as_uint(NEG_FILL_F);
    }
    __syncthreads();
    if (l15 == 0) {   // lanes 0,16,32,48 hold row results for their quad
        #pragma unroll
        for (int r = 0; r < 4; ++r)
            #pragma unroll
            for (int e = 0; e < 4; ++e) {
                const int lr = wy * 64 + r * 16 + quad * 4 + e;
                atomicMax(&srhp[lr], __float_as_int(rmax[r][e]));
                atomicMin(&srhn[lr], __float_as_uint(rmin[r][e]));
            }
    }
    if (quad == 0) {  // lanes 0..15 hold col results
        #pragma unroll
        for (int c = 0; c < 4; ++c) {
            const int lc = wx * 64 + c * 16 + l15;
            atomicMax(&schp[lc], __float_as_int(cmax[c]));
            atomicMin(&schn[lc], __float_as_uint(cmin[c]));
        }
    }
    __syncthreads();
    if (tid < 128) {
        float rp = __int_as_float(srhp[tid]);
        float rn = __uint_as_float(srhn[tid]);
        const float cp = __int_as_float(schp[tid]);
        const float cn = __uint_as_float(schn[tid]);
        if (ib == jb) {
            pHP[(size_t)jb * BN + i0 + tid] = fmaxf(rp, cp);   // diagonal: combine
            pHN[(size_t)jb * BN + i0 + tid] = fminf(rn, cn);
        } else {
            pHP[(size_t)jb * BN + i0 + tid] = rp;   // row-part -> slot jb
            pHN[(size_t)jb * BN + i0 + tid] = rn;
            pHP[(size_t)ib * BN + j0 + tid] = cp;   // col-part -> slot ib
            pHN[(size_t)ib * BN + j0 + tid] = cn;
        }
    }
}

// ------- reduce: fold 32 d^2 partial slots per row (4-way parallel per row),
//         sqrt once, accumulate loss, last block finalizes ----------------------
__global__ __launch_bounds__(256) void tl_reduce(const float* __restrict__ pHP,
                                                 const float* __restrict__ pHN,
                                                 float* __restrict__ red,
                                                 float* __restrict__ out) {
    __shared__ float shp[4][64], shn[4][64];
    const int rl = threadIdx.x & 63;                 // row within block
    const int g  = threadIdx.x >> 6;                 // slot-group 0..3 (8 slots each)
    const int i  = blockIdx.x * 64 + rl;
    float hp2 = -1.0f, hn2 = NEG_FILL_F;
    #pragma unroll
    for (int q = 0; q < 8; ++q) {
        const int s = g * 8 + q;
        hp2 = fmaxf(hp2, pHP[(size_t)s * BN + i]);   // coalesced per 64-lane group
        hn2 = fminf(hn2, pHN[(size_t)s * BN + i]);
    }
    shp[g][rl] = hp2;
    shn[g][rl] = hn2;
    __syncthreads();
    if (g == 0) {                                    // wave 0 finishes 64 rows
        #pragma unroll
        for (int k = 1; k < 4; ++k) {
            hp2 = fmaxf(hp2, shp[k][rl]);
            hn2 = fminf(hn2, shn[k][rl]);
        }
        const bool valid = (hp2 >= 0.0f) && (hn2 < NEG_FILL_F);  // has_pos && has_neg
        const float hp = sqrtf(fmaxf(hp2, 0.0f));    // sqrt(max d^2) == max d (monotone)
        const float hn = sqrtf(hn2);
        const float per = fmaxf(hp - hn + MARGIN_F, 0.0f);
        float s_ = valid ? per : 0.0f;
        float c_ = valid ? 1.0f : 0.0f;
        #pragma unroll
        for (int m = 32; m; m >>= 1) {
            s_ += __shfl_xor(s_, m, 64);
            c_ += __shfl_xor(c_, m, 64);
        }
        if (rl == 0) {
            atomicAdd(&red[0], s_);
            atomicAdd(&red[1], c_);
            __threadfence();
            const unsigned ticket = atomicAdd(reinterpret_cast<unsigned*>(&red[2]), 1u);
            if (ticket == gridDim.x - 1) {           // last block finalizes
                const float S2 = atomicAdd(&red[0], 0.0f);   // atomic read (RMW-ordered)
                const float C2 = atomicAdd(&red[1], 0.0f);
                out[0] = (C2 > 0.0f) ? (S2 / fmaxf(C2, 1.0f)) : 0.0f;
            }
        }
    }
}

extern "C" void kernel_launch(void* const* d_in, const int* in_sizes, int n_in,
                              void* d_out, int out_size, void* d_ws, size_t ws_size,
                              hipStream_t stream) {
    const float* E      = (const float*)d_in[0];
    const int*   labels = (const int*)d_in[1];

    float*  ws    = (float*)d_ws;
    float*  norms = ws;                            // [4096] f32
    float*  red   = ws + 4096;                     // [3] f32 (sum, cnt, ticket)
    float*  pHP   = ws + 8192;                     // [32][4096] f32 = 512 KB (d^2)
    float*  pHN   = ws + 8192 + NBLK * BN;         // [32][4096] f32 = 512 KB (d^2)
    ushort* Eh    = (ushort*)(ws + 8192 + 2 * NBLK * BN);  // [32][4096][8] f16 = 2 MB

    tl_prep<<<BN / 4, 256, 0, stream>>>(E, norms, red, Eh);
    tl_main<<<NPAIR, 256, 0, stream>>>(Eh, labels, norms, pHP, pHN);
    tl_reduce<<<BN / 64, 256, 0, stream>>>(pHP, pHN, red, (float*)d_out);
}